// Round 6
// baseline (692.548 us; speedup 1.0000x reference)
//
#include <hip/hip_runtime.h>

#define HW 256
#define PW 258              // padded width/height
#define PP (PW * PW)        // padded pixels per image
#define NPIX (HW * HW)

using short8 = __attribute__((ext_vector_type(8))) short;
using short4v = __attribute__((ext_vector_type(4))) short;
using f32x4 = __attribute__((ext_vector_type(4))) float;
using h4 = __attribute__((ext_vector_type(4))) _Float16;
using h8 = __attribute__((ext_vector_type(8))) _Float16;

// async global->LDS, 16B per lane; LDS dest = wave-uniform base + lane*16
#define GLD_LDS(g, l)                                                  \
  __builtin_amdgcn_global_load_lds(                                    \
      (const __attribute__((address_space(1))) void*)(g),              \
      (__attribute__((address_space(3))) void*)(l), 16, 0, 0)

static __device__ __forceinline__ ushort f2bf(float f) {
  unsigned u = __float_as_uint(f);
  unsigned r = (u + 0x7FFFu + ((u >> 16) & 1u)) >> 16;  // RNE
  return (ushort)r;
}
static __device__ __forceinline__ float bf2f(ushort u) {
  return __uint_as_float(((unsigned)u) << 16);
}

// ---------------------------------------------------------------------------
// pack data_with_est [4,6,256,256] fp32 NCHW -> xp padded [4][258][258][8] bf16
// ---------------------------------------------------------------------------
__global__ void pack_in_k(const float* __restrict__ din, ushort* __restrict__ xp) {
  int i = blockIdx.x * 256 + threadIdx.x;  // 0 .. 262143
  int b = i >> 16;
  int px = i & 65535;
  int y = px >> 8, x = px & 255;
  short8 v;
#pragma unroll
  for (int z = 0; z < 8; ++z) v[z] = 0;
#pragma unroll
  for (int ic = 0; ic < 6; ++ic)
    v[ic] = (short)f2bf(din[(b * 6 + ic) * NPIX + px]);
  *(short8*)&xp[((size_t)b * PP + (size_t)(y + 1) * PW + (x + 1)) * 8] = v;
}

// ---------------------------------------------------------------------------
// zero the 1-px halo ring of x, y (64ch) and xp (8ch) padded buffers
// ---------------------------------------------------------------------------
__global__ void zero_halo_k(ushort* __restrict__ x, ushort* __restrict__ y,
                            ushort* __restrict__ xp) {
  int i = blockIdx.x * 256 + threadIdx.x;
  if (i >= 4 * 1028) return;
  int b = i / 1028;
  int h = i - b * 1028;
  int py, px;
  if (h < 258) { py = 0; px = h; }
  else if (h < 516) { py = 257; px = h - 258; }
  else if (h < 772) { py = h - 516 + 1; px = 0; }
  else { py = h - 772 + 1; px = 257; }
  size_t p = (size_t)b * PP + (size_t)py * PW + px;
  short8 z;
#pragma unroll
  for (int k = 0; k < 8; ++k) z[k] = 0;
#pragma unroll
  for (int c8 = 0; c8 < 8; ++c8) {
    *(short8*)&x[p * 64 + c8 * 8] = z;
    *(short8*)&y[p * 64 + c8 * 8] = z;
  }
  *(short8*)&xp[p * 8] = z;
}

// ---------------------------------------------------------------------------
// pack conv weights [OC,CIN,3,3] fp32 -> MFMA A-fragment order bf16:
//   wf[((ks*NG + g)*64 + lane)*8 + j]
//   oc = g*16 + (lane&15);  k = ks*32 + (lane>>4)*8 + j;  t = k/CPAD; ic = k%CPAD
// ---------------------------------------------------------------------------
__global__ void pack_wfrag_k(const float* __restrict__ w,
                             ushort* __restrict__ wf, int OC, int CIN,
                             int CPAD, int NG, int total) {
  int i = blockIdx.x * 256 + threadIdx.x;
  if (i >= total) return;
  int j = i & 7;
  int lane = (i >> 3) & 63;
  int rest = i >> 9;
  int g = rest % NG;
  int ks = rest / NG;
  int oc = g * 16 + (lane & 15);
  int k = ks * 32 + (lane >> 4) * 8 + j;
  int t = k / CPAD;
  int ic = k - t * CPAD;
  float v = 0.f;
  if (oc < OC && t < 9 && ic < CIN) v = w[(oc * CIN + ic) * 9 + t];
  wf[i] = f2bf(v);
}

// ---------------------------------------------------------------------------
// Implicit-GEMM 3x3 conv, bf16 MFMA 16x16x32, padded NHWC.
// Block 256 = 4 waves = 4 output rows; wave = 64 oc x 64 px (4mt x 4nt).
// Weights: LDS (4x cross-wave reuse), 3-ks chunks double-buffered.
// Activations: DIRECT GLOBAL 16B loads (tile is L1-resident; no staging,
// no swizzle, no staging barrier). LDS = 24.6 KB only -> 3 blocks/CU.
// ---------------------------------------------------------------------------
template <int C, int KS, bool RELU, bool RESID>
__global__ __launch_bounds__(256, 3) void conv_mfma_k(
    const ushort* __restrict__ in, const ushort* __restrict__ wf,
    const float* __restrict__ bias, const ushort* __restrict__ resid,
    ushort* __restrict__ out) {
  constexpr int NCH = KS / 3;               // weight chunks (6 or 1)
  constexpr int NBUF = (NCH > 1) ? 2 : 1;
  constexpr int CHW = 3 * 4 * 64 * 8;       // halfwords per chunk (12.3KB)
  __shared__ __align__(16) ushort wLds[NBUF * CHW];

  const int tid = threadIdx.x;
  const int wave = tid >> 6, lane = tid & 63;
  const int quad = lane >> 4, l15 = lane & 15;
  const int x0 = blockIdx.x * 64, y0 = blockIdx.y * 4, b = blockIdx.z;
  const ushort* inb = in + (size_t)b * PP * C;

  // stage weight chunk 0 (identity copy, fragment order)
#pragma unroll
  for (int r = 0; r < 3; ++r) {
    int s0 = r * 256 + wave * 64;
    GLD_LDS(wf + (size_t)(s0 + lane) * 8, &wLds[s0 * 8]);
  }
  __syncthreads();

  f32x4 acc[4][4];
#pragma unroll
  for (int mt = 0; mt < 4; ++mt)
#pragma unroll
    for (int nt = 0; nt < 4; ++nt)
#pragma unroll
      for (int r = 0; r < 4; ++r) acc[mt][nt][r] = 0.f;

#pragma unroll
  for (int ch = 0; ch < NCH; ++ch) {
    if (ch + 1 < NCH) {  // DMA next weight chunk while computing this one
      const ushort* src = wf + (size_t)(ch + 1) * CHW;
      ushort* dst = &wLds[((ch + 1) % NBUF) * CHW];
#pragma unroll
      for (int r = 0; r < 3; ++r) {
        int s0 = r * 256 + wave * 64;
        GLD_LDS(src + (size_t)(s0 + lane) * 8, dst + s0 * 8);
      }
    }
    const ushort* wb = &wLds[(ch % NBUF) * CHW];
#pragma unroll
    for (int ksl = 0; ksl < 3; ++ksl) {
      const int ks = ch * 3 + ksl;
      short8 A[4], B[4];
#pragma unroll
      for (int mt = 0; mt < 4; ++mt)
        A[mt] = *(const short8*)&wb[((ksl * 4 + mt) * 64 + lane) * 8];
      int t, chunk;
      if (C == 64) {
        t = ks >> 1;
        chunk = ((ks & 1) << 2) + quad;
      } else {
        t = ks * 4 + quad;
        if (t > 8) t = 8;  // dummy taps: A rows are zero
        chunk = 0;
      }
      int dy = t / 3, dx = t - (t / 3) * 3;
#pragma unroll
      for (int nt = 0; nt < 4; ++nt) {
        const ushort* gp =
            inb + ((size_t)(y0 + wave + dy) * PW + (x0 + nt * 16 + l15 + dx)) *
                      C + chunk * 8;
        B[nt] = *(const short8*)gp;  // L1-served, 16B coalesced
      }
#pragma unroll
      for (int nt = 0; nt < 4; ++nt)
#pragma unroll
        for (int mt = 0; mt < 4; ++mt)
          acc[mt][nt] = __builtin_amdgcn_mfma_f32_16x16x32_bf16(
              A[mt], B[nt], acc[mt][nt], 0, 0, 0);
    }
    if (NCH > 1) __syncthreads();
  }

  // epilogue: C/D layout col=l15 (pixel), row=quad*4+reg (oc)
  const int yw = y0 + wave;
#pragma unroll
  for (int mt = 0; mt < 4; ++mt) {
    const float4 bb = *(const float4*)&bias[mt * 16 + quad * 4];
#pragma unroll
    for (int nt = 0; nt < 4; ++nt) {
      int px = x0 + nt * 16 + l15;
      size_t base = ((size_t)b * PP + (size_t)(yw + 1) * PW + (px + 1)) * 64 +
                    mt * 16 + quad * 4;
      float v0 = acc[mt][nt][0] + bb.x;
      float v1 = acc[mt][nt][1] + bb.y;
      float v2 = acc[mt][nt][2] + bb.z;
      float v3 = acc[mt][nt][3] + bb.w;
      if (RELU) {
        v0 = fmaxf(v0, 0.f); v1 = fmaxf(v1, 0.f);
        v2 = fmaxf(v2, 0.f); v3 = fmaxf(v3, 0.f);
      }
      if (RESID) {
        short4v rv = *(const short4v*)&resid[base];
        v0 += bf2f((ushort)rv[0]); v1 += bf2f((ushort)rv[1]);
        v2 += bf2f((ushort)rv[2]); v3 += bf2f((ushort)rv[3]);
      }
      short4v o;
      o[0] = (short)f2bf(v0); o[1] = (short)f2bf(v1);
      o[2] = (short)f2bf(v2); o[3] = (short)f2bf(v3);
      *(short4v*)&out[base] = o;
    }
  }
}

// ---------------------------------------------------------------------------
// Fused out-conv (64->225 pad 256) + abs-softmax + 15x15 kernel-conv.
// Block 256 = 4 waves; wave w = oc [64w, 64w+64) x 64 px (4mt x 4nt).
// Weights streamed per-ks in 16KB LDS chunks, double-buffered.
// Activations direct from global (L1). coreSh aliases wLds, stride 280
// (bank-spread ~2-way). LDS ~50KB -> 3 blocks/CU.
// ---------------------------------------------------------------------------
__global__ __launch_bounds__(256, 3) void out_kc_k(
    const ushort* __restrict__ x, const ushort* __restrict__ wf,
    const float* __restrict__ b_out, const float* __restrict__ data,
    float* __restrict__ pred) {
  constexpr int CHW = 16 * 64 * 8;  // halfwords per 1-ks chunk (16KB)
  __shared__ __align__(16) char uni[64 * 280 * 2];  // wLds 2x16KB | coreSh alias
  __shared__ float dsh[3][15][78];
  __shared__ float bsh[256];
  ushort* wLds = (ushort*)uni;
  _Float16* coreSh = (_Float16*)uni;  // [64 px][280]

  const int tid = threadIdx.x;
  const int wave = tid >> 6, lane = tid & 63;
  const int quad = lane >> 4, l15 = lane & 15;
  const int x0 = blockIdx.x * 64, y = blockIdx.y, b = blockIdx.z;

  // stage weight chunk 0
#pragma unroll
  for (int r = 0; r < 4; ++r) {
    int s0 = r * 256 + wave * 64;
    GLD_LDS(wf + (size_t)(s0 + lane) * 8, &wLds[s0 * 8]);
  }
  bsh[tid] = (tid < 225) ? b_out[tid] : 0.f;
  // stage data halo [3][15][78] fp32 (pad 7, zero-fill; data unpadded)
  for (int i = tid; i < 3 * 15 * 78; i += 256) {
    int ch = i / 1170;
    int rem = i - ch * 1170;
    int r = rem / 78;
    int cc = rem - r * 78;
    int gy = y - 7 + r, gx = x0 - 7 + cc;
    float v = 0.f;
    if ((unsigned)gy < (unsigned)HW && (unsigned)gx < (unsigned)HW)
      v = data[((b * 3 + ch) << 16) + (gy << 8) + gx];
    dsh[ch][r][cc] = v;
  }
  __syncthreads();

  f32x4 acc[4][4];
#pragma unroll
  for (int mt = 0; mt < 4; ++mt)
#pragma unroll
    for (int nt = 0; nt < 4; ++nt)
#pragma unroll
      for (int r = 0; r < 4; ++r) acc[mt][nt][r] = 0.f;

#pragma unroll
  for (int ks = 0; ks < 18; ++ks) {
    if (ks + 1 < 18) {  // DMA next weight chunk
      const ushort* src = wf + (size_t)(ks + 1) * CHW;
      ushort* dst = &wLds[((ks + 1) & 1) * CHW];
#pragma unroll
      for (int r = 0; r < 4; ++r) {
        int s0 = r * 256 + wave * 64;
        GLD_LDS(src + (size_t)(s0 + lane) * 8, dst + s0 * 8);
      }
    }
    const ushort* wb = &wLds[(ks & 1) * CHW];
    short8 A[4], B[4];
#pragma unroll
    for (int mt = 0; mt < 4; ++mt)
      A[mt] = *(const short8*)&wb[((wave * 4 + mt) * 64 + lane) * 8];
    int t = ks >> 1;
    int dy = t / 3, dx = t - (t / 3) * 3;
    int chunk = ((ks & 1) << 2) + quad;
#pragma unroll
    for (int nt = 0; nt < 4; ++nt) {
      const ushort* gp = x + ((size_t)b * PP + (size_t)(y + dy) * PW +
                              (x0 + nt * 16 + l15 + dx)) * 64 + chunk * 8;
      B[nt] = *(const short8*)gp;  // L1-served
    }
#pragma unroll
    for (int nt = 0; nt < 4; ++nt)
#pragma unroll
      for (int mt = 0; mt < 4; ++mt)
        acc[mt][nt] = __builtin_amdgcn_mfma_f32_16x16x32_bf16(
            A[mt], B[nt], acc[mt][nt], 0, 0, 0);
    __syncthreads();  // wLds buffer swap
  }

  // producer: |core + bias| (masked -> -1e4) as fp16, row stride 280
#pragma unroll
  for (int mt = 0; mt < 4; ++mt) {
    int c0 = wave * 64 + mt * 16 + quad * 4;
#pragma unroll
    for (int nt = 0; nt < 4; ++nt) {
      int px = nt * 16 + l15;
      h4 hv;
#pragma unroll
      for (int r = 0; r < 4; ++r) {
        int c = c0 + r;
        float a = acc[mt][nt][r] + bsh[c];
        a = (c < 225) ? fabsf(a) : -1e4f;
        hv[r] = (_Float16)a;
      }
      *(h4*)&coreSh[px * 280 + c0] = hv;
    }
  }
  __syncthreads();

  // consumer: lane -> (px = wave*16+l15, channel quarter = quad)
  const int px = wave * 16 + l15;
  const int cbase = quad * 64;
  h8 vals[8];
#pragma unroll
  for (int v = 0; v < 8; ++v)
    vals[v] = *(h8*)&coreSh[px * 280 + cbase + v * 8];

  float m = 0.f;  // |core| >= 0; masked entries negative
#pragma unroll
  for (int v = 0; v < 8; ++v)
#pragma unroll
    for (int z = 0; z < 8; ++z) m = fmaxf(m, (float)vals[v][z]);
  m = fmaxf(m, __shfl_xor(m, 16));
  m = fmaxf(m, __shfl_xor(m, 32));

  float l = 0.f, p0 = 0.f, p1 = 0.f, p2 = 0.f;
#pragma unroll
  for (int v = 0; v < 8; ++v)
#pragma unroll
    for (int z = 0; z < 8; ++z) {
      int c = cbase + v * 8 + z;
      float a = (float)vals[v][z];
      float e = __expf(a - m);  // masked channels underflow to 0
      l += e;
      if (c < 225) {
        int di = (int)(((unsigned)c * 34953u) >> 19);  // c/15 exact
        int dj = c - di * 15;
        p0 += e * dsh[0][di][px + dj];
        p1 += e * dsh[1][di][px + dj];
        p2 += e * dsh[2][di][px + dj];
      }
    }
  l += __shfl_xor(l, 16);  l += __shfl_xor(l, 32);
  p0 += __shfl_xor(p0, 16); p0 += __shfl_xor(p0, 32);
  p1 += __shfl_xor(p1, 16); p1 += __shfl_xor(p1, 32);
  p2 += __shfl_xor(p2, 16); p2 += __shfl_xor(p2, 32);

  if (quad == 0) {
    float inv = 1.f / l;
    int pix = (y << 8) + x0 + px;
    pred[((b * 3 + 0) << 16) + pix] = p0 * inv;
    pred[((b * 3 + 1) << 16) + pix] = p1 * inv;
    pred[((b * 3 + 2) << 16) + pix] = p2 * inv;
  }
}

// ---------------------------------------------------------------------------
// data -> d_out[0 : 786432] verbatim copy (float4)
// ---------------------------------------------------------------------------
__global__ void copy_k(const float4* __restrict__ src, float4* __restrict__ dst,
                       int n4) {
  int i = blockIdx.x * blockDim.x + threadIdx.x;
  if (i < n4) dst[i] = src[i];
}

extern "C" void kernel_launch(void* const* d_in, const int* in_sizes, int n_in,
                              void* d_out, int out_size, void* d_ws,
                              size_t ws_size, hipStream_t stream) {
  const float* data_with_est = (const float*)d_in[0];
  const float* data = (const float*)d_in[1];
  const float* w_first = (const float*)d_in[2];
  const float* b_first = (const float*)d_in[3];
  const float* wa[3] = {(const float*)d_in[4], (const float*)d_in[8],
                        (const float*)d_in[12]};
  const float* ba[3] = {(const float*)d_in[5], (const float*)d_in[9],
                        (const float*)d_in[13]};
  const float* wb[3] = {(const float*)d_in[6], (const float*)d_in[10],
                        (const float*)d_in[14]};
  const float* bb[3] = {(const float*)d_in[7], (const float*)d_in[11],
                        (const float*)d_in[15]};
  const float* w_out = (const float*)d_in[16];
  const float* b_out = (const float*)d_in[17];

  float* out = (float*)d_out;
  float* pred = out + 4 * 3 * NPIX;

  // workspace layout (ushort units)
  ushort* x = (ushort*)d_ws;                 // 4*PP*64
  ushort* y = x + (size_t)4 * PP * 64;       // 4*PP*64
  ushort* xp = y + (size_t)4 * PP * 64;      // 4*PP*8
  ushort* Wp1 = xp + (size_t)4 * PP * 8;     // 6144   (first conv, frag order)
  ushort* Wpr = Wp1 + 6144;                  // 6*36864 (res convs, frag order)
  ushort* Wpo = Wpr + 6 * 36864;             // 147456 (out conv, frag order)

  // packs + halo zeroing
  pack_in_k<<<1024, 256, 0, stream>>>(data_with_est, xp);
  zero_halo_k<<<17, 256, 0, stream>>>(x, y, xp);
  pack_wfrag_k<<<24, 256, 0, stream>>>(w_first, Wp1, 64, 6, 8, 4, 6144);
  for (int i = 0; i < 3; ++i) {
    pack_wfrag_k<<<144, 256, 0, stream>>>(wa[i], Wpr + (2 * i) * 36864, 64, 64,
                                          64, 4, 36864);
    pack_wfrag_k<<<144, 256, 0, stream>>>(wb[i], Wpr + (2 * i + 1) * 36864, 64,
                                          64, 64, 4, 36864);
  }
  pack_wfrag_k<<<576, 256, 0, stream>>>(w_out, Wpo, 225, 64, 64, 16, 147456);

  dim3 cgrid(4, 64, 4), cblk(256);
  // first conv 6->64 (C padded to 8, K padded to 96)
  conv_mfma_k<8, 3, false, false>
      <<<cgrid, cblk, 0, stream>>>(xp, Wp1, b_first, nullptr, x);
  // 3 residual blocks
  for (int i = 0; i < 3; ++i) {
    conv_mfma_k<64, 18, true, false><<<cgrid, cblk, 0, stream>>>(
        x, Wpr + (2 * i) * 36864, ba[i], nullptr, y);
    conv_mfma_k<64, 18, false, true><<<cgrid, cblk, 0, stream>>>(
        y, Wpr + (2 * i + 1) * 36864, bb[i], x, x);
  }
  // fused out-conv + softmax + kernel-conv
  out_kc_k<<<dim3(4, HW, 4), 256, 0, stream>>>(x, Wpo, b_out, data, pred);
  // data passthrough
  int n4 = 4 * 3 * NPIX / 4;
  copy_k<<<(n4 + 255) / 256, 256, 0, stream>>>((const float4*)data,
                                               (float4*)out, n4);
}

// Round 7
// 466.838 us; speedup vs baseline: 1.4835x; 1.4835x over previous
//
#include <hip/hip_runtime.h>

#define HW 256
#define PW 258              // padded width/height
#define PP (PW * PW)        // padded pixels per image
#define NPIX (HW * HW)

using short8 = __attribute__((ext_vector_type(8))) short;
using short4v = __attribute__((ext_vector_type(4))) short;
using f32x4 = __attribute__((ext_vector_type(4))) float;
using h4 = __attribute__((ext_vector_type(4))) _Float16;
using h8 = __attribute__((ext_vector_type(8))) _Float16;

// async global->LDS, 16B per lane; LDS dest = wave-uniform base + lane*16
#define GLD_LDS(g, l)                                                  \
  __builtin_amdgcn_global_load_lds(                                    \
      (const __attribute__((address_space(1))) void*)(g),              \
      (__attribute__((address_space(3))) void*)(l), 16, 0, 0)

static __device__ __forceinline__ ushort f2bf(float f) {
  unsigned u = __float_as_uint(f);
  unsigned r = (u + 0x7FFFu + ((u >> 16) & 1u)) >> 16;  // RNE
  return (ushort)r;
}
static __device__ __forceinline__ float bf2f(ushort u) {
  return __uint_as_float(((unsigned)u) << 16);
}

// ---------------------------------------------------------------------------
// pack data_with_est [4,6,256,256] fp32 NCHW -> xp padded [4][258][258][8] bf16
// ---------------------------------------------------------------------------
__global__ void pack_in_k(const float* __restrict__ din, ushort* __restrict__ xp) {
  int i = blockIdx.x * 256 + threadIdx.x;  // 0 .. 262143
  int b = i >> 16;
  int px = i & 65535;
  int y = px >> 8, x = px & 255;
  short8 v;
#pragma unroll
  for (int z = 0; z < 8; ++z) v[z] = 0;
#pragma unroll
  for (int ic = 0; ic < 6; ++ic)
    v[ic] = (short)f2bf(din[(b * 6 + ic) * NPIX + px]);
  *(short8*)&xp[((size_t)b * PP + (size_t)(y + 1) * PW + (x + 1)) * 8] = v;
}

// ---------------------------------------------------------------------------
// zero the 1-px halo ring of x, y (64ch) and xp (8ch) padded buffers
// ---------------------------------------------------------------------------
__global__ void zero_halo_k(ushort* __restrict__ x, ushort* __restrict__ y,
                            ushort* __restrict__ xp) {
  int i = blockIdx.x * 256 + threadIdx.x;
  if (i >= 4 * 1028) return;
  int b = i / 1028;
  int h = i - b * 1028;
  int py, px;
  if (h < 258) { py = 0; px = h; }
  else if (h < 516) { py = 257; px = h - 258; }
  else if (h < 772) { py = h - 516 + 1; px = 0; }
  else { py = h - 772 + 1; px = 257; }
  size_t p = (size_t)b * PP + (size_t)py * PW + px;
  short8 z;
#pragma unroll
  for (int k = 0; k < 8; ++k) z[k] = 0;
#pragma unroll
  for (int c8 = 0; c8 < 8; ++c8) {
    *(short8*)&x[p * 64 + c8 * 8] = z;
    *(short8*)&y[p * 64 + c8 * 8] = z;
  }
  *(short8*)&xp[p * 8] = z;
}

// ---------------------------------------------------------------------------
// pack conv weights [OC,CIN,3,3] fp32 -> MFMA A-fragment order bf16:
//   wf[((ks*NG + g)*64 + lane)*8 + j]
//   oc = g*16 + (lane&15);  k = ks*32 + (lane>>4)*8 + j;  t = k/CPAD; ic = k%CPAD
// ---------------------------------------------------------------------------
__global__ void pack_wfrag_k(const float* __restrict__ w,
                             ushort* __restrict__ wf, int OC, int CIN,
                             int CPAD, int NG, int total) {
  int i = blockIdx.x * 256 + threadIdx.x;
  if (i >= total) return;
  int j = i & 7;
  int lane = (i >> 3) & 63;
  int rest = i >> 9;
  int g = rest % NG;
  int ks = rest / NG;
  int oc = g * 16 + (lane & 15);
  int k = ks * 32 + (lane >> 4) * 8 + j;
  int t = k / CPAD;
  int ic = k - t * CPAD;
  float v = 0.f;
  if (oc < OC && t < 9 && ic < CIN) v = w[(oc * CIN + ic) * 9 + t];
  wf[i] = f2bf(v);
}

// ---------------------------------------------------------------------------
// Implicit-GEMM 3x3 conv, bf16 MFMA 16x16x32, padded NHWC.
// Block 256 = 4 waves = 4 output rows; wave = 64 oc x 64 px (4mt x 4nt).
// B (activations): LDS, swizzled, staged once (one barrier total).
// A (weights): register rolling window W=6, refilled from L2 with 6-ks
// prefetch distance -> NO barriers and no latency-critical loads in K-loop.
// __launch_bounds__(256,2): 256-VGPR budget so the window stays in registers.
// ---------------------------------------------------------------------------
template <int C, int KS, bool RELU, bool RESID>
__global__ __launch_bounds__(256, 2) void conv_mfma_k(
    const ushort* __restrict__ in, const ushort* __restrict__ wf,
    const float* __restrict__ bias, const ushort* __restrict__ resid,
    ushort* __restrict__ out) {
  constexpr int CV = C / 8;                 // 16B chunks per pixel
  constexpr int SROW = 66 * CV;             // slots per staged row
  constexpr int TOT = 6 * SROW;             // live slots (4 rows + halo)
  constexpr int LSLOT = ((TOT + 63) / 64) * 64;
  constexpr int W = (KS > 6) ? 6 : KS;      // A register window depth
  __shared__ __align__(16) ushort xs[LSLOT * 8];

  const int tid = threadIdx.x;
  const int wave = tid >> 6, lane = tid & 63;
  const int quad = lane >> 4, l15 = lane & 15;
  const int x0 = blockIdx.x * 64, y0 = blockIdx.y * 4, b = blockIdx.z;
  const ushort* inb = in + (size_t)b * PP * C;
  const ushort* wfl = wf + (size_t)lane * 8;  // lane-fixed base

  // stage activation tile: padded rows y0..y0+5, cols x0..x0+65 (swizzled)
  for (int s0 = wave * 64; s0 < TOT; s0 += 256) {
    int s = s0 + lane;
    int row, col, chunk;
    if (C == 64) {
      row = s / SROW;
      int r = s - row * SROW;
      col = r >> 3;
      chunk = (r & 7) ^ (col & 7);  // inverse swizzle on source
    } else {
      row = s / 66;
      col = s - row * 66;
      chunk = 0;
    }
    GLD_LDS(inb + ((size_t)(y0 + row) * PW + (x0 + col)) * C + chunk * 8,
            &xs[(size_t)s0 * 8]);
  }

  // preload A window (per-wave VGPR loads, wave-contiguous 1KB each)
  short8 Wa[4][W];
  auto loadA = [&](int slot, int ks) {
#pragma unroll
    for (int mt = 0; mt < 4; ++mt)
      Wa[mt][slot] = *(const short8*)&wfl[(size_t)(ks * 4 + mt) * 512];
  };
#pragma unroll
  for (int ks = 0; ks < W; ++ks) loadA(ks, ks);

  __syncthreads();  // xs ready (the only barrier)

  f32x4 acc[4][4];
#pragma unroll
  for (int mt = 0; mt < 4; ++mt)
#pragma unroll
    for (int nt = 0; nt < 4; ++nt)
#pragma unroll
      for (int r = 0; r < 4; ++r) acc[mt][nt][r] = 0.f;

  auto loadB = [&](short8* B, int ks) {
    int t, chunk;
    if (C == 64) {
      t = ks >> 1;
      chunk = ((ks & 1) << 2) + quad;
    } else {
      t = ks * 4 + quad;
      if (t > 8) t = 8;  // dummy taps: A rows are zero
      chunk = 0;
    }
    int dy = t / 3, dx = t - (t / 3) * 3;
#pragma unroll
    for (int nt = 0; nt < 4; ++nt) {
      int c = nt * 16 + l15 + dx;
      int slot = (C == 64)
                     ? ((wave + dy) * SROW + c * 8 + (chunk ^ (c & 7)))
                     : ((wave + dy) * 66 + c);
      B[nt] = *(const short8*)&xs[(size_t)slot * 8];
    }
  };

  short8 B0[4], B1[4];
  loadB(B0, 0);
#pragma unroll
  for (int ks = 0; ks < KS; ++ks) {
    if (ks + 1 < KS) loadB(B1, ks + 1);
    const int slot = ks % W;  // compile-time constant under full unroll
#pragma unroll
    for (int nt = 0; nt < 4; ++nt)
#pragma unroll
      for (int mt = 0; mt < 4; ++mt)
        acc[mt][nt] = __builtin_amdgcn_mfma_f32_16x16x32_bf16(
            Wa[mt][slot], B0[nt], acc[mt][nt], 0, 0, 0);
    if (ks + W < KS) loadA(slot, ks + W);  // rolling refill (6-ks lead)
#pragma unroll
    for (int nt = 0; nt < 4; ++nt) B0[nt] = B1[nt];
  }

  // epilogue: C/D layout col=l15 (pixel), row=quad*4+reg (oc)
  const int yw = y0 + wave;
#pragma unroll
  for (int mt = 0; mt < 4; ++mt) {
    const float4 bb = *(const float4*)&bias[mt * 16 + quad * 4];
#pragma unroll
    for (int nt = 0; nt < 4; ++nt) {
      int px = x0 + nt * 16 + l15;
      size_t base = ((size_t)b * PP + (size_t)(yw + 1) * PW + (px + 1)) * 64 +
                    mt * 16 + quad * 4;
      float v0 = acc[mt][nt][0] + bb.x;
      float v1 = acc[mt][nt][1] + bb.y;
      float v2 = acc[mt][nt][2] + bb.z;
      float v3 = acc[mt][nt][3] + bb.w;
      if (RELU) {
        v0 = fmaxf(v0, 0.f); v1 = fmaxf(v1, 0.f);
        v2 = fmaxf(v2, 0.f); v3 = fmaxf(v3, 0.f);
      }
      if (RESID) {
        short4v rv = *(const short4v*)&resid[base];
        v0 += bf2f((ushort)rv[0]); v1 += bf2f((ushort)rv[1]);
        v2 += bf2f((ushort)rv[2]); v3 += bf2f((ushort)rv[3]);
      }
      short4v o;
      o[0] = (short)f2bf(v0); o[1] = (short)f2bf(v1);
      o[2] = (short)f2bf(v2); o[3] = (short)f2bf(v3);
      *(short4v*)&out[base] = o;
    }
  }
}

// ---------------------------------------------------------------------------
// Fused out-conv (64->225 pad 256) + abs-softmax + 15x15 kernel-conv.
// Block 256 = 4 waves; wave w = oc [64w, 64w+64) x 64 px (4mt x 4nt).
// B from LDS (swizzled), A = register rolling window from L2 (per-wave oc
// group). 3 barriers total (stage, pre-coreSh, post-coreSh).
// ---------------------------------------------------------------------------
__global__ __launch_bounds__(256, 2) void out_kc_k(
    const ushort* __restrict__ x, const ushort* __restrict__ wf,
    const float* __restrict__ b_out, const float* __restrict__ data,
    float* __restrict__ pred) {
  // uni: xs (1584 slots * 16B = 25344B) aliased by coreSh [64][264] fp16
  __shared__ __align__(16) char uni[64 * 264 * 2];
  __shared__ float dsh[3][15][78];
  __shared__ float bsh[256];
  ushort* xs = (ushort*)uni;
  _Float16* coreSh = (_Float16*)uni;

  const int tid = threadIdx.x;
  const int wave = tid >> 6, lane = tid & 63;
  const int quad = lane >> 4, l15 = lane & 15;
  const int x0 = blockIdx.x * 64, y = blockIdx.y, b = blockIdx.z;
  const ushort* wfl = wf + (size_t)lane * 8;

  // stage x tile: 3 padded rows y..y+2, cols x0..x0+65 (swizzled)
  for (int s0 = wave * 64; s0 < 3 * 528; s0 += 256) {
    int s = s0 + lane;
    int row = s / 528;
    int r = s - row * 528;
    int col = r >> 3;
    int chunk = (r & 7) ^ (col & 7);
    const ushort* g = x + ((size_t)b * PP + (size_t)(y + row) * PW +
                           (x0 + col)) * 64 + chunk * 8;
    GLD_LDS(g, &xs[(size_t)s0 * 8]);
  }
  bsh[tid] = (tid < 225) ? b_out[tid] : 0.f;
  // stage data halo [3][15][78] fp32 (pad 7, zero-fill; data unpadded)
  for (int i = tid; i < 3 * 15 * 78; i += 256) {
    int ch = i / 1170;
    int rem = i - ch * 1170;
    int r = rem / 78;
    int cc = rem - r * 78;
    int gy = y - 7 + r, gx = x0 - 7 + cc;
    float v = 0.f;
    if ((unsigned)gy < (unsigned)HW && (unsigned)gx < (unsigned)HW)
      v = data[((b * 3 + ch) << 16) + (gy << 8) + gx];
    dsh[ch][r][cc] = v;
  }

  // preload A window (wave w -> oc group w: g = wave*4 + mt, NG = 16)
  short8 Wa[4][6];
  auto loadA = [&](int slot, int ks) {
#pragma unroll
    for (int mt = 0; mt < 4; ++mt)
      Wa[mt][slot] =
          *(const short8*)&wfl[(size_t)((ks * 16 + wave * 4 + mt)) * 512];
  };
#pragma unroll
  for (int ks = 0; ks < 6; ++ks) loadA(ks, ks);

  __syncthreads();

  f32x4 acc[4][4];
#pragma unroll
  for (int mt = 0; mt < 4; ++mt)
#pragma unroll
    for (int nt = 0; nt < 4; ++nt)
#pragma unroll
      for (int r = 0; r < 4; ++r) acc[mt][nt][r] = 0.f;

  auto loadB = [&](short8* B, int ks) {
    int t = ks >> 1;
    int dy = t / 3, dx = t - (t / 3) * 3;
    int chunk = ((ks & 1) << 2) + quad;
#pragma unroll
    for (int nt = 0; nt < 4; ++nt) {
      int c = nt * 16 + l15 + dx;
      int slot = dy * 528 + c * 8 + (chunk ^ (c & 7));
      B[nt] = *(const short8*)&xs[(size_t)slot * 8];
    }
  };

  short8 B0[4], B1[4];
  loadB(B0, 0);
#pragma unroll
  for (int ks = 0; ks < 18; ++ks) {
    if (ks + 1 < 18) loadB(B1, ks + 1);
    const int slot = ks % 6;
#pragma unroll
    for (int nt = 0; nt < 4; ++nt)
#pragma unroll
      for (int mt = 0; mt < 4; ++mt)
        acc[mt][nt] = __builtin_amdgcn_mfma_f32_16x16x32_bf16(
            Wa[mt][slot], B0[nt], acc[mt][nt], 0, 0, 0);
    if (ks + 6 < 18) loadA(slot, ks + 6);
#pragma unroll
    for (int nt = 0; nt < 4; ++nt) B0[nt] = B1[nt];
  }
  __syncthreads();  // retire xs reads before aliasing as coreSh

  // producer: |core + bias| (masked -> -1e4) as fp16, row stride 264
#pragma unroll
  for (int mt = 0; mt < 4; ++mt) {
    int c0 = wave * 64 + mt * 16 + quad * 4;
#pragma unroll
    for (int nt = 0; nt < 4; ++nt) {
      int px = nt * 16 + l15;
      h4 hv;
#pragma unroll
      for (int r = 0; r < 4; ++r) {
        int c = c0 + r;
        float a = acc[mt][nt][r] + bsh[c];
        a = (c < 225) ? fabsf(a) : -1e4f;
        hv[r] = (_Float16)a;
      }
      *(h4*)&coreSh[px * 264 + c0] = hv;
    }
  }
  __syncthreads();

  // consumer: lane -> (px = wave*16+l15, channel quarter = quad)
  const int px = wave * 16 + l15;
  const int cbase = quad * 64;
  h8 vals[8];
#pragma unroll
  for (int v = 0; v < 8; ++v)
    vals[v] = *(h8*)&coreSh[px * 264 + cbase + v * 8];

  float m = 0.f;  // |core| >= 0; masked entries negative
#pragma unroll
  for (int v = 0; v < 8; ++v)
#pragma unroll
    for (int z = 0; z < 8; ++z) m = fmaxf(m, (float)vals[v][z]);
  m = fmaxf(m, __shfl_xor(m, 16));
  m = fmaxf(m, __shfl_xor(m, 32));

  float l = 0.f, p0 = 0.f, p1 = 0.f, p2 = 0.f;
#pragma unroll
  for (int v = 0; v < 8; ++v)
#pragma unroll
    for (int z = 0; z < 8; ++z) {
      int c = cbase + v * 8 + z;
      float a = (float)vals[v][z];
      float e = __expf(a - m);  // masked channels underflow to 0
      l += e;
      if (c < 225) {
        int di = (int)(((unsigned)c * 34953u) >> 19);  // c/15 exact
        int dj = c - di * 15;
        p0 += e * dsh[0][di][px + dj];
        p1 += e * dsh[1][di][px + dj];
        p2 += e * dsh[2][di][px + dj];
      }
    }
  l += __shfl_xor(l, 16);  l += __shfl_xor(l, 32);
  p0 += __shfl_xor(p0, 16); p0 += __shfl_xor(p0, 32);
  p1 += __shfl_xor(p1, 16); p1 += __shfl_xor(p1, 32);
  p2 += __shfl_xor(p2, 16); p2 += __shfl_xor(p2, 32);

  if (quad == 0) {
    float inv = 1.f / l;
    int pix = (y << 8) + x0 + px;
    pred[((b * 3 + 0) << 16) + pix] = p0 * inv;
    pred[((b * 3 + 1) << 16) + pix] = p1 * inv;
    pred[((b * 3 + 2) << 16) + pix] = p2 * inv;
  }
}

// ---------------------------------------------------------------------------
// data -> d_out[0 : 786432] verbatim copy (float4)
// ---------------------------------------------------------------------------
__global__ void copy_k(const float4* __restrict__ src, float4* __restrict__ dst,
                       int n4) {
  int i = blockIdx.x * blockDim.x + threadIdx.x;
  if (i < n4) dst[i] = src[i];
}

extern "C" void kernel_launch(void* const* d_in, const int* in_sizes, int n_in,
                              void* d_out, int out_size, void* d_ws,
                              size_t ws_size, hipStream_t stream) {
  const float* data_with_est = (const float*)d_in[0];
  const float* data = (const float*)d_in[1];
  const float* w_first = (const float*)d_in[2];
  const float* b_first = (const float*)d_in[3];
  const float* wa[3] = {(const float*)d_in[4], (const float*)d_in[8],
                        (const float*)d_in[12]};
  const float* ba[3] = {(const float*)d_in[5], (const float*)d_in[9],
                        (const float*)d_in[13]};
  const float* wb[3] = {(const float*)d_in[6], (const float*)d_in[10],
                        (const float*)d_in[14]};
  const float* bb[3] = {(const float*)d_in[7], (const float*)d_in[11],
                        (const float*)d_in[15]};
  const float* w_out = (const float*)d_in[16];
  const float* b_out = (const float*)d_in[17];

  float* out = (float*)d_out;
  float* pred = out + 4 * 3 * NPIX;

  // workspace layout (ushort units)
  ushort* x = (ushort*)d_ws;                 // 4*PP*64
  ushort* y = x + (size_t)4 * PP * 64;       // 4*PP*64
  ushort* xp = y + (size_t)4 * PP * 64;      // 4*PP*8
  ushort* Wp1 = xp + (size_t)4 * PP * 8;     // 6144   (first conv, frag order)
  ushort* Wpr = Wp1 + 6144;                  // 6*36864 (res convs, frag order)
  ushort* Wpo = Wpr + 6 * 36864;             // 147456 (out conv, frag order)

  // packs + halo zeroing
  pack_in_k<<<1024, 256, 0, stream>>>(data_with_est, xp);
  zero_halo_k<<<17, 256, 0, stream>>>(x, y, xp);
  pack_wfrag_k<<<24, 256, 0, stream>>>(w_first, Wp1, 64, 6, 8, 4, 6144);
  for (int i = 0; i < 3; ++i) {
    pack_wfrag_k<<<144, 256, 0, stream>>>(wa[i], Wpr + (2 * i) * 36864, 64, 64,
                                          64, 4, 36864);
    pack_wfrag_k<<<144, 256, 0, stream>>>(wb[i], Wpr + (2 * i + 1) * 36864, 64,
                                          64, 64, 4, 36864);
  }
  pack_wfrag_k<<<576, 256, 0, stream>>>(w_out, Wpo, 225, 64, 64, 16, 147456);

  dim3 cgrid(4, 64, 4), cblk(256);
  // first conv 6->64 (C padded to 8, K padded to 96)
  conv_mfma_k<8, 3, false, false>
      <<<cgrid, cblk, 0, stream>>>(xp, Wp1, b_first, nullptr, x);
  // 3 residual blocks
  for (int i = 0; i < 3; ++i) {
    conv_mfma_k<64, 18, true, false><<<cgrid, cblk, 0, stream>>>(
        x, Wpr + (2 * i) * 36864, ba[i], nullptr, y);
    conv_mfma_k<64, 18, false, true><<<cgrid, cblk, 0, stream>>>(
        y, Wpr + (2 * i + 1) * 36864, bb[i], x, x);
  }
  // fused out-conv + softmax + kernel-conv
  out_kc_k<<<dim3(4, HW, 4), 256, 0, stream>>>(x, Wpo, b_out, data, pred);
  // data passthrough
  int n4 = 4 * 3 * NPIX / 4;
  copy_k<<<(n4 + 255) / 256, 256, 0, stream>>>((const float4*)data,
                                               (float4*)out, n4);
}

// Round 8
// 443.133 us; speedup vs baseline: 1.5628x; 1.0535x over previous
//
#include <hip/hip_runtime.h>

#define HW 256
#define PW 258              // padded width/height
#define PP (PW * PW)        // padded pixels per image
#define NPIX (HW * HW)

using short8 = __attribute__((ext_vector_type(8))) short;
using short4v = __attribute__((ext_vector_type(4))) short;
using f32x4 = __attribute__((ext_vector_type(4))) float;
using h4 = __attribute__((ext_vector_type(4))) _Float16;

// async global->LDS, 16B per lane; LDS dest = wave-uniform base + lane*16
#define GLD_LDS(g, l)                                                  \
  __builtin_amdgcn_global_load_lds(                                    \
      (const __attribute__((address_space(1))) void*)(g),              \
      (__attribute__((address_space(3))) void*)(l), 16, 0, 0)

static __device__ __forceinline__ ushort f2bf(float f) {
  unsigned u = __float_as_uint(f);
  unsigned r = (u + 0x7FFFu + ((u >> 16) & 1u)) >> 16;  // RNE
  return (ushort)r;
}
static __device__ __forceinline__ float bf2f(ushort u) {
  return __uint_as_float(((unsigned)u) << 16);
}

// ---------------------------------------------------------------------------
// prep_pack_k: fused pack_in + zero_halo + data->out copy (one launch).
// blocks [0,1024): pack data_with_est -> xp;  [1024,1041): halo zeroing;
// [1041,1809): copy data -> d_out[0:786432].
// ---------------------------------------------------------------------------
__global__ void prep_pack_k(const float* __restrict__ din,
                            ushort* __restrict__ xp, ushort* __restrict__ x,
                            ushort* __restrict__ y,
                            const float4* __restrict__ data4,
                            float4* __restrict__ out4) {
  int blk = blockIdx.x, tid = threadIdx.x;
  if (blk < 1024) {
    int i = blk * 256 + tid;  // 0..262143
    int b = i >> 16;
    int px = i & 65535;
    int yy = px >> 8, xx = px & 255;
    short8 v;
#pragma unroll
    for (int z = 0; z < 8; ++z) v[z] = 0;
#pragma unroll
    for (int ic = 0; ic < 6; ++ic)
      v[ic] = (short)f2bf(din[(b * 6 + ic) * NPIX + px]);
    *(short8*)&xp[((size_t)b * PP + (size_t)(yy + 1) * PW + (xx + 1)) * 8] = v;
  } else if (blk < 1041) {
    int i = (blk - 1024) * 256 + tid;
    if (i >= 4 * 1028) return;
    int b = i / 1028;
    int h = i - b * 1028;
    int py, px;
    if (h < 258) { py = 0; px = h; }
    else if (h < 516) { py = 257; px = h - 258; }
    else if (h < 772) { py = h - 516 + 1; px = 0; }
    else { py = h - 772 + 1; px = 257; }
    size_t p = (size_t)b * PP + (size_t)py * PW + px;
    short8 z;
#pragma unroll
    for (int k = 0; k < 8; ++k) z[k] = 0;
#pragma unroll
    for (int c8 = 0; c8 < 8; ++c8) {
      *(short8*)&x[p * 64 + c8 * 8] = z;
      *(short8*)&y[p * 64 + c8 * 8] = z;
    }
    *(short8*)&xp[p * 8] = z;
  } else {
    int i = (blk - 1041) * 256 + tid;
    if (i < 196608) out4[i] = data4[i];
  }
}

// ---------------------------------------------------------------------------
// prep_w_k: all 8 weight packs in one launch (MFMA A-fragment order):
//   wf[((ks*NG + g)*64 + lane)*8 + j]
//   oc = g*16 + (lane&15); k = ks*32 + (lane>>4)*8 + j; t = k/CPAD; ic = k%CPAD
// ---------------------------------------------------------------------------
struct W8 { const float* w[8]; };

static __device__ __forceinline__ void pack_one(const float* __restrict__ w,
                                                ushort* __restrict__ wf, int OC,
                                                int CIN, int CPAD, int i,
                                                int total) {
  if (i >= total) return;
  int j = i & 7;
  int lane = (i >> 3) & 63;
  int rest = i >> 9;
  int NG = total >> 9;          // per-ks groups * ks... (not needed directly)
  (void)NG;
  // rest = ks*NGroups + g ; group decode needs NGroups:
  // we pass CPAD-dependent NGroups via total/(KS*512); recompute:
  // For our shapes NG is 4 (64oc) or 16 (256oc):
  int NGr = (OC > 64) ? 16 : 4;
  int g = rest % NGr;
  int ks = rest / NGr;
  int oc = g * 16 + (lane & 15);
  int k = ks * 32 + (lane >> 4) * 8 + j;
  int t = k / CPAD;
  int ic = k - t * CPAD;
  float v = 0.f;
  if (oc < OC && t < 9 && ic < CIN) v = w[(oc * CIN + ic) * 9 + t];
  wf[i] = f2bf(v);
}

__global__ void prep_w_k(W8 ws, ushort* __restrict__ base) {
  int blk = blockIdx.x, tid = threadIdx.x;
  if (blk < 24) {
    pack_one(ws.w[0], base, 64, 6, 8, blk * 256 + tid, 6144);
  } else if (blk < 888) {
    int seg = (blk - 24) / 144;               // 0..5
    int i = ((blk - 24) - seg * 144) * 256 + tid;
    pack_one(ws.w[1 + seg], base + 6144 + seg * 36864, 64, 64, 64, i, 36864);
  } else {
    int i = (blk - 888) * 256 + tid;
    pack_one(ws.w[7], base + 227328, 225, 64, 64, i, 147456);
  }
}

// ---------------------------------------------------------------------------
// Implicit-GEMM 3x3 conv, bf16 MFMA 16x16x32, padded NHWC.
// Block 256 = 4 waves = 4 output rows; wave = 64 oc x 64 px (4mt x 4nt).
// B (activations): LDS, swizzled, staged once (one barrier total).
// A (weights): register rolling window W=4 from L2, 4-ks prefetch lead.
// Ping-pong B register buffers indexed by ks&1 (no copies).
// ---------------------------------------------------------------------------
template <int C, int KS, bool RELU, bool RESID>
__global__ __launch_bounds__(256, 2) void conv_mfma_k(
    const ushort* __restrict__ in, const ushort* __restrict__ wf,
    const float* __restrict__ bias, const ushort* __restrict__ resid,
    ushort* __restrict__ out) {
  constexpr int CV = C / 8;                 // 16B chunks per pixel
  constexpr int SROW = 66 * CV;             // slots per staged row
  constexpr int TOT = 6 * SROW;             // live slots (4 rows + halo)
  constexpr int LSLOT = ((TOT + 63) / 64) * 64;
  constexpr int W = (KS > 4) ? 4 : KS;      // A register window depth
  __shared__ __align__(16) ushort xs[LSLOT * 8];

  const int tid = threadIdx.x;
  const int wave = tid >> 6, lane = tid & 63;
  const int quad = lane >> 4, l15 = lane & 15;
  const int x0 = blockIdx.x * 64, y0 = blockIdx.y * 4, b = blockIdx.z;
  const ushort* inb = in + (size_t)b * PP * C;
  const ushort* wfl = wf + (size_t)lane * 8;  // lane-fixed base

  // stage activation tile: padded rows y0..y0+5, cols x0..x0+65 (swizzled)
  for (int s0 = wave * 64; s0 < TOT; s0 += 256) {
    int s = s0 + lane;
    int row, col, chunk;
    if (C == 64) {
      row = s / SROW;
      int r = s - row * SROW;
      col = r >> 3;
      chunk = (r & 7) ^ (col & 7);  // inverse swizzle on source
    } else {
      row = s / 66;
      col = s - row * 66;
      chunk = 0;
    }
    GLD_LDS(inb + ((size_t)(y0 + row) * PW + (x0 + col)) * C + chunk * 8,
            &xs[(size_t)s0 * 8]);
  }

  // preload A window (per-wave VGPR loads, wave-contiguous 1KB each)
  short8 Wa[4][W];
  auto loadA = [&](int slot, int ks) {
#pragma unroll
    for (int mt = 0; mt < 4; ++mt)
      Wa[mt][slot] = *(const short8*)&wfl[(size_t)(ks * 4 + mt) * 512];
  };
#pragma unroll
  for (int ks = 0; ks < W; ++ks) loadA(ks, ks);

  __syncthreads();  // xs ready (the only barrier)

  f32x4 acc[4][4];
#pragma unroll
  for (int mt = 0; mt < 4; ++mt)
#pragma unroll
    for (int nt = 0; nt < 4; ++nt)
#pragma unroll
      for (int r = 0; r < 4; ++r) acc[mt][nt][r] = 0.f;

  auto loadB = [&](short8* B, int ks) {
    int t, chunk;
    if (C == 64) {
      t = ks >> 1;
      chunk = ((ks & 1) << 2) + quad;
    } else {
      t = ks * 4 + quad;
      if (t > 8) t = 8;  // dummy taps: A rows are zero
      chunk = 0;
    }
    int dy = t / 3, dx = t - (t / 3) * 3;
#pragma unroll
    for (int nt = 0; nt < 4; ++nt) {
      int c = nt * 16 + l15 + dx;
      int slot = (C == 64)
                     ? ((wave + dy) * SROW + c * 8 + (chunk ^ (c & 7)))
                     : ((wave + dy) * 66 + c);
      B[nt] = *(const short8*)&xs[(size_t)slot * 8];
    }
  };

  short8 Bbuf[2][4];
  loadB(Bbuf[0], 0);
#pragma unroll
  for (int ks = 0; ks < KS; ++ks) {
    if (ks + 1 < KS) loadB(Bbuf[(ks + 1) & 1], ks + 1);
    const int slot = ks % W;  // compile-time under full unroll
#pragma unroll
    for (int nt = 0; nt < 4; ++nt)
#pragma unroll
      for (int mt = 0; mt < 4; ++mt)
        acc[mt][nt] = __builtin_amdgcn_mfma_f32_16x16x32_bf16(
            Wa[mt][slot], Bbuf[ks & 1][nt], acc[mt][nt], 0, 0, 0);
    if (ks + W < KS) loadA(slot, ks + W);  // rolling refill (W-ks lead)
  }

  // epilogue: C/D layout col=l15 (pixel), row=quad*4+reg (oc)
  const int yw = y0 + wave;
#pragma unroll
  for (int mt = 0; mt < 4; ++mt) {
    const float4 bb = *(const float4*)&bias[mt * 16 + quad * 4];
#pragma unroll
    for (int nt = 0; nt < 4; ++nt) {
      int px = x0 + nt * 16 + l15;
      size_t base = ((size_t)b * PP + (size_t)(yw + 1) * PW + (px + 1)) * 64 +
                    mt * 16 + quad * 4;
      float v0 = acc[mt][nt][0] + bb.x;
      float v1 = acc[mt][nt][1] + bb.y;
      float v2 = acc[mt][nt][2] + bb.z;
      float v3 = acc[mt][nt][3] + bb.w;
      if (RELU) {
        v0 = fmaxf(v0, 0.f); v1 = fmaxf(v1, 0.f);
        v2 = fmaxf(v2, 0.f); v3 = fmaxf(v3, 0.f);
      }
      if (RESID) {
        short4v rv = *(const short4v*)&resid[base];
        v0 += bf2f((ushort)rv[0]); v1 += bf2f((ushort)rv[1]);
        v2 += bf2f((ushort)rv[2]); v3 += bf2f((ushort)rv[3]);
      }
      short4v o;
      o[0] = (short)f2bf(v0); o[1] = (short)f2bf(v1);
      o[2] = (short)f2bf(v2); o[3] = (short)f2bf(v3);
      *(short4v*)&out[base] = o;
    }
  }
}

// ---------------------------------------------------------------------------
// Fused out-conv (64->225 pad 256) + abs-softmax + 15x15 kernel-conv.
// Block 256 = 4 waves; wave w = oc [64w, 64w+64) x 64 px (4mt x 4nt).
// B from LDS (swizzled), A = register rolling window from L2.
// Consumer v2: lane -> (px = wave*16+l15, row-group = quad: tap rows
// 4q..4q+3 = channels 60q..60q+59). coreSh read as 15x h4; data tile stored
// TRANSPOSED fp16 dshT[ch][col][20] so one ds_read_b64 serves the 4 rows of
// a (ch,dj) tap column. All dj/rr indices compile-time.
// ---------------------------------------------------------------------------
__global__ __launch_bounds__(256, 2) void out_kc_k(
    const ushort* __restrict__ x, const ushort* __restrict__ wf,
    const float* __restrict__ b_out, const float* __restrict__ data,
    float* __restrict__ pred) {
  // uni: xs (1584 slots * 16B = 25344B) aliased by coreSh [64][264] fp16
  __shared__ __align__(16) char uni[64 * 264 * 2];
  __shared__ __align__(16) _Float16 dshT[3 * 80 * 20];  // [ch][col][row(16)+pad]
  __shared__ float bsh[256];
  ushort* xs = (ushort*)uni;
  _Float16* coreSh = (_Float16*)uni;

  const int tid = threadIdx.x;
  const int wave = tid >> 6, lane = tid & 63;
  const int quad = lane >> 4, l15 = lane & 15;
  const int x0 = blockIdx.x * 64, y = blockIdx.y, b = blockIdx.z;
  const ushort* wfl = wf + (size_t)lane * 8;

  // stage x tile: 3 padded rows y..y+2, cols x0..x0+65 (swizzled)
  for (int s0 = wave * 64; s0 < 3 * 528; s0 += 256) {
    int s = s0 + lane;
    int row = s / 528;
    int r = s - row * 528;
    int col = r >> 3;
    int chunk = (r & 7) ^ (col & 7);
    const ushort* g = x + ((size_t)b * PP + (size_t)(y + row) * PW +
                           (x0 + col)) * 64 + chunk * 8;
    GLD_LDS(g, &xs[(size_t)s0 * 8]);
  }
  bsh[tid] = (tid < 225) ? b_out[tid] : 0.f;
  // stage data tile transposed: dshT[(ch*80+col)*20 + r] = data[gy=y-7+r][gx=x0-7+col]
  // rows 0..15 (row 15 only feeds e=0 channels; staged anyway -> finite)
  for (int i = tid; i < 3 * 16 * 78; i += 256) {
    int ch = i / 1248;
    int rem = i - ch * 1248;
    int r = rem / 78;
    int col = rem - r * 78;
    int gy = y - 7 + r, gx = x0 - 7 + col;
    float v = 0.f;
    if ((unsigned)gy < (unsigned)HW && (unsigned)gx < (unsigned)HW)
      v = data[((b * 3 + ch) << 16) + (gy << 8) + gx];
    dshT[(ch * 80 + col) * 20 + r] = (_Float16)v;
  }

  // preload A window (wave w -> oc group w: g = wave*4 + mt, NG = 16)
  short8 Wa[4][4];
  auto loadA = [&](int slot, int ks) {
#pragma unroll
    for (int mt = 0; mt < 4; ++mt)
      Wa[mt][slot] =
          *(const short8*)&wfl[(size_t)((ks * 16 + wave * 4 + mt)) * 512];
  };
#pragma unroll
  for (int ks = 0; ks < 4; ++ks) loadA(ks, ks);

  __syncthreads();

  f32x4 acc[4][4];
#pragma unroll
  for (int mt = 0; mt < 4; ++mt)
#pragma unroll
    for (int nt = 0; nt < 4; ++nt)
#pragma unroll
      for (int r = 0; r < 4; ++r) acc[mt][nt][r] = 0.f;

  auto loadB = [&](short8* B, int ks) {
    int t = ks >> 1;
    int dy = t / 3, dx = t - (t / 3) * 3;
    int chunk = ((ks & 1) << 2) + quad;
#pragma unroll
    for (int nt = 0; nt < 4; ++nt) {
      int c = nt * 16 + l15 + dx;
      int slot = dy * 528 + c * 8 + (chunk ^ (c & 7));
      B[nt] = *(const short8*)&xs[(size_t)slot * 8];
    }
  };

  short8 Bbuf[2][4];
  loadB(Bbuf[0], 0);
#pragma unroll
  for (int ks = 0; ks < 18; ++ks) {
    if (ks + 1 < 18) loadB(Bbuf[(ks + 1) & 1], ks + 1);
    const int slot = ks % 4;
#pragma unroll
    for (int nt = 0; nt < 4; ++nt)
#pragma unroll
      for (int mt = 0; mt < 4; ++mt)
        acc[mt][nt] = __builtin_amdgcn_mfma_f32_16x16x32_bf16(
            Wa[mt][slot], Bbuf[ks & 1][nt], acc[mt][nt], 0, 0, 0);
    if (ks + 4 < 18) loadA(slot, ks + 4);
  }
  __syncthreads();  // retire xs reads before aliasing as coreSh

  // producer: |core + bias| (masked -> -1e4) as fp16, row stride 264
#pragma unroll
  for (int mt = 0; mt < 4; ++mt) {
    int c0 = wave * 64 + mt * 16 + quad * 4;
#pragma unroll
    for (int nt = 0; nt < 4; ++nt) {
      int px = nt * 16 + l15;
      h4 hv;
#pragma unroll
      for (int r = 0; r < 4; ++r) {
        int c = c0 + r;
        float a = acc[mt][nt][r] + bsh[c];
        a = (c < 225) ? fabsf(a) : -1e4f;
        hv[r] = (_Float16)a;
      }
      *(h4*)&coreSh[px * 264 + c0] = hv;
    }
  }
  __syncthreads();

  // consumer v2: px = wave*16+l15; quad = tap-row group (rows 4q..4q+3,
  // channels 60q..60q+59). 15x h4 coreSh + 45x b64 dshT per lane.
  const int px = wave * 16 + l15;
  const int q = quad;
  h4 vals4[15];
#pragma unroll
  for (int k = 0; k < 15; ++k)
    vals4[k] = *(h4*)&coreSh[px * 264 + q * 60 + k * 4];

  float m = 0.f;  // |core| >= 0; masked entries negative
#pragma unroll
  for (int k = 0; k < 15; ++k)
#pragma unroll
    for (int z = 0; z < 4; ++z) m = fmaxf(m, (float)vals4[k][z]);
  m = fmaxf(m, __shfl_xor(m, 16));
  m = fmaxf(m, __shfl_xor(m, 32));

  float e[60];
  float l = 0.f;
#pragma unroll
  for (int k = 0; k < 15; ++k)
#pragma unroll
    for (int z = 0; z < 4; ++z) {
      float t = __expf((float)vals4[k][z] - m);  // masked -> exactly 0
      e[k * 4 + z] = t;
      l += t;
    }

  float p0 = 0.f, p1 = 0.f, p2 = 0.f;
#pragma unroll
  for (int dj = 0; dj < 15; ++dj) {
    // one b64 per channel gives the 4 tap-rows of this column
    h4 d0 = *(h4*)&dshT[(0 * 80 + px + dj) * 20 + 4 * q];
    h4 d1 = *(h4*)&dshT[(1 * 80 + px + dj) * 20 + 4 * q];
    h4 d2 = *(h4*)&dshT[(2 * 80 + px + dj) * 20 + 4 * q];
#pragma unroll
    for (int rr = 0; rr < 4; ++rr) {
      float ev = e[rr * 15 + dj];
      p0 += ev * (float)d0[rr];
      p1 += ev * (float)d1[rr];
      p2 += ev * (float)d2[rr];
    }
  }
  l += __shfl_xor(l, 16);  l += __shfl_xor(l, 32);
  p0 += __shfl_xor(p0, 16); p0 += __shfl_xor(p0, 32);
  p1 += __shfl_xor(p1, 16); p1 += __shfl_xor(p1, 32);
  p2 += __shfl_xor(p2, 16); p2 += __shfl_xor(p2, 32);

  if (q == 0) {
    float inv = 1.f / l;
    int pix = (y << 8) + x0 + px;
    pred[((b * 3 + 0) << 16) + pix] = p0 * inv;
    pred[((b * 3 + 1) << 16) + pix] = p1 * inv;
    pred[((b * 3 + 2) << 16) + pix] = p2 * inv;
  }
}

extern "C" void kernel_launch(void* const* d_in, const int* in_sizes, int n_in,
                              void* d_out, int out_size, void* d_ws,
                              size_t ws_size, hipStream_t stream) {
  const float* data_with_est = (const float*)d_in[0];
  const float* data = (const float*)d_in[1];
  const float* b_first = (const float*)d_in[3];
  const float* ba[3] = {(const float*)d_in[5], (const float*)d_in[9],
                        (const float*)d_in[13]};
  const float* bb[3] = {(const float*)d_in[7], (const float*)d_in[11],
                        (const float*)d_in[15]};
  const float* b_out = (const float*)d_in[17];

  float* out = (float*)d_out;
  float* pred = out + 4 * 3 * NPIX;

  // workspace layout (ushort units)
  ushort* x = (ushort*)d_ws;                 // 4*PP*64
  ushort* y = x + (size_t)4 * PP * 64;       // 4*PP*64
  ushort* xp = y + (size_t)4 * PP * 64;      // 4*PP*8
  ushort* Wb = xp + (size_t)4 * PP * 8;      // packed weights base:
  ushort* Wp1 = Wb;                          //   +0      (6144)
  ushort* Wpr = Wb + 6144;                   //   +6144   (6*36864)
  ushort* Wpo = Wb + 227328;                 //   +227328 (147456)

  // fused prep (2 launches total)
  prep_pack_k<<<1809, 256, 0, stream>>>(data_with_est, xp, x, y,
                                        (const float4*)data, (float4*)out);
  W8 ws;
  ws.w[0] = (const float*)d_in[2];
  ws.w[1] = (const float*)d_in[4];  ws.w[2] = (const float*)d_in[6];
  ws.w[3] = (const float*)d_in[8];  ws.w[4] = (const float*)d_in[10];
  ws.w[5] = (const float*)d_in[12]; ws.w[6] = (const float*)d_in[14];
  ws.w[7] = (const float*)d_in[16];
  prep_w_k<<<1464, 256, 0, stream>>>(ws, Wb);

  dim3 cgrid(4, 64, 4), cblk(256);
  // first conv 6->64 (C padded to 8, K padded to 96)
  conv_mfma_k<8, 3, false, false>
      <<<cgrid, cblk, 0, stream>>>(xp, Wp1, b_first, nullptr, x);
  // 3 residual blocks
  for (int i = 0; i < 3; ++i) {
    conv_mfma_k<64, 18, true, false><<<cgrid, cblk, 0, stream>>>(
        x, Wpr + (2 * i) * 36864, ba[i], nullptr, y);
    conv_mfma_k<64, 18, false, true><<<cgrid, cblk, 0, stream>>>(
        y, Wpr + (2 * i + 1) * 36864, bb[i], x, x);
  }
  // fused out-conv + softmax + kernel-conv
  out_kc_k<<<dim3(4, HW, 4), 256, 0, stream>>>(x, Wpo, b_out, data, pred);
}

// Round 9
// 418.483 us; speedup vs baseline: 1.6549x; 1.0589x over previous
//
#include <hip/hip_runtime.h>

#define HW 256
#define PW 258              // padded width/height
#define PP (PW * PW)        // padded pixels per image
#define NPIX (HW * HW)

using short8 = __attribute__((ext_vector_type(8))) short;
using short4v = __attribute__((ext_vector_type(4))) short;
using f32x4 = __attribute__((ext_vector_type(4))) float;
using h4 = __attribute__((ext_vector_type(4))) _Float16;

// async global->LDS, 16B per lane; LDS dest = wave-uniform base + lane*16
#define GLD_LDS(g, l)                                                  \
  __builtin_amdgcn_global_load_lds(                                    \
      (const __attribute__((address_space(1))) void*)(g),              \
      (__attribute__((address_space(3))) void*)(l), 16, 0, 0)

static __device__ __forceinline__ ushort f2bf(float f) {
  unsigned u = __float_as_uint(f);
  unsigned r = (u + 0x7FFFu + ((u >> 16) & 1u)) >> 16;  // RNE
  return (ushort)r;
}
static __device__ __forceinline__ float bf2f(ushort u) {
  return __uint_as_float(((unsigned)u) << 16);
}

// ---------------------------------------------------------------------------
// prep_pack_k: fused pack_in + zero_halo + data->out copy (one launch).
// ---------------------------------------------------------------------------
__global__ void prep_pack_k(const float* __restrict__ din,
                            ushort* __restrict__ xp, ushort* __restrict__ x,
                            ushort* __restrict__ y,
                            const float4* __restrict__ data4,
                            float4* __restrict__ out4) {
  int blk = blockIdx.x, tid = threadIdx.x;
  if (blk < 1024) {
    int i = blk * 256 + tid;  // 0..262143
    int b = i >> 16;
    int px = i & 65535;
    int yy = px >> 8, xx = px & 255;
    short8 v;
#pragma unroll
    for (int z = 0; z < 8; ++z) v[z] = 0;
#pragma unroll
    for (int ic = 0; ic < 6; ++ic)
      v[ic] = (short)f2bf(din[(b * 6 + ic) * NPIX + px]);
    *(short8*)&xp[((size_t)b * PP + (size_t)(yy + 1) * PW + (xx + 1)) * 8] = v;
  } else if (blk < 1041) {
    int i = (blk - 1024) * 256 + tid;
    if (i >= 4 * 1028) return;
    int b = i / 1028;
    int h = i - b * 1028;
    int py, px;
    if (h < 258) { py = 0; px = h; }
    else if (h < 516) { py = 257; px = h - 258; }
    else if (h < 772) { py = h - 516 + 1; px = 0; }
    else { py = h - 772 + 1; px = 257; }
    size_t p = (size_t)b * PP + (size_t)py * PW + px;
    short8 z;
#pragma unroll
    for (int k = 0; k < 8; ++k) z[k] = 0;
#pragma unroll
    for (int c8 = 0; c8 < 8; ++c8) {
      *(short8*)&x[p * 64 + c8 * 8] = z;
      *(short8*)&y[p * 64 + c8 * 8] = z;
    }
    *(short8*)&xp[p * 8] = z;
  } else {
    int i = (blk - 1041) * 256 + tid;
    if (i < 196608) out4[i] = data4[i];
  }
}

// ---------------------------------------------------------------------------
// prep_w_k: all 8 weight packs in one launch (MFMA A-fragment order):
//   wf[((ks*NG + g)*64 + lane)*8 + j]
//   oc = g*16 + (lane&15); k = ks*32 + (lane>>4)*8 + j; t = k/CPAD; ic = k%CPAD
// ---------------------------------------------------------------------------
struct W8 { const float* w[8]; };

static __device__ __forceinline__ void pack_one(const float* __restrict__ w,
                                                ushort* __restrict__ wf, int OC,
                                                int CIN, int CPAD, int i,
                                                int total) {
  if (i >= total) return;
  int j = i & 7;
  int lane = (i >> 3) & 63;
  int rest = i >> 9;
  int NGr = (OC > 64) ? 16 : 4;
  int g = rest % NGr;
  int ks = rest / NGr;
  int oc = g * 16 + (lane & 15);
  int k = ks * 32 + (lane >> 4) * 8 + j;
  int t = k / CPAD;
  int ic = k - t * CPAD;
  float v = 0.f;
  if (oc < OC && t < 9 && ic < CIN) v = w[(oc * CIN + ic) * 9 + t];
  wf[i] = f2bf(v);
}

__global__ void prep_w_k(W8 ws, ushort* __restrict__ base) {
  int blk = blockIdx.x, tid = threadIdx.x;
  if (blk < 24) {
    pack_one(ws.w[0], base, 64, 6, 8, blk * 256 + tid, 6144);
  } else if (blk < 888) {
    int seg = (blk - 24) / 144;               // 0..5
    int i = ((blk - 24) - seg * 144) * 256 + tid;
    pack_one(ws.w[1 + seg], base + 6144 + seg * 36864, 64, 64, 64, i, 36864);
  } else {
    int i = (blk - 888) * 256 + tid;
    pack_one(ws.w[7], base + 227328, 225, 64, 64, i, 147456);
  }
}

// ---------------------------------------------------------------------------
// Implicit-GEMM 3x3 conv, bf16 MFMA 16x16x32, padded NHWC. v2 (small-tile):
// Tile = 2 rows x 64 px; block 256 = 4 waves = (row, ocHalf); each wave
// 32 oc x 64 px (2 mt x 4 nt). xs = 4 rows x 66 cols = 33.8 KB.
// A: register window W=4 (2x4 short8 = 32 VGPR). B: LDS, ping-pong regs.
// __launch_bounds__(256,4): 128-VGPR budget -> 4 blocks/CU for inter-block
// latency hiding (the staging DMA of block n+1 overlaps K-loop of block n).
// ---------------------------------------------------------------------------
template <int C, int KS, bool RELU, bool RESID>
__global__ __launch_bounds__(256, 4) void conv_mfma_k(
    const ushort* __restrict__ in, const ushort* __restrict__ wf,
    const float* __restrict__ bias, const ushort* __restrict__ resid,
    ushort* __restrict__ out) {
  constexpr int CV = C / 8;                 // 16B chunks per pixel
  constexpr int SROW = 66 * CV;             // slots per staged row
  constexpr int TOT = 4 * SROW;             // live slots (2 rows + halo)
  constexpr int LSLOT = ((TOT + 63) / 64) * 64;
  constexpr int W = (KS > 4) ? 4 : KS;      // A register window depth
  __shared__ __align__(16) ushort xs[LSLOT * 8];

  const int tid = threadIdx.x;
  const int wave = tid >> 6, lane = tid & 63;
  const int quad = lane >> 4, l15 = lane & 15;
  const int rowIdx = wave & 1, ocH = wave >> 1;
  const int x0 = blockIdx.x * 64, y0 = blockIdx.y * 2, b = blockIdx.z;
  const ushort* inb = in + (size_t)b * PP * C;
  const ushort* wfl = wf + (size_t)lane * 8;  // lane-fixed base

  // stage activation tile: padded rows y0..y0+3, cols x0..x0+65 (swizzled)
  for (int s0 = wave * 64; s0 < TOT; s0 += 256) {
    int s = s0 + lane;
    int row, col, chunk;
    if (C == 64) {
      row = s / SROW;
      int r = s - row * SROW;
      col = r >> 3;
      chunk = (r & 7) ^ (col & 7);  // inverse swizzle on source
    } else {
      row = s / 66;
      col = s - row * 66;
      chunk = 0;
    }
    GLD_LDS(inb + ((size_t)(y0 + row) * PW + (x0 + col)) * C + chunk * 8,
            &xs[(size_t)s0 * 8]);
  }

  // preload A window (per-wave VGPR loads; g = ocH*2 + mt, NG = 4)
  short8 Wa[2][W];
  auto loadA = [&](int slot, int ks) {
#pragma unroll
    for (int mt = 0; mt < 2; ++mt)
      Wa[mt][slot] =
          *(const short8*)&wfl[(size_t)(ks * 4 + ocH * 2 + mt) * 512];
  };
#pragma unroll
  for (int ks = 0; ks < W; ++ks) loadA(ks, ks);

  __syncthreads();  // xs ready (the only barrier)

  f32x4 acc[2][4];
#pragma unroll
  for (int mt = 0; mt < 2; ++mt)
#pragma unroll
    for (int nt = 0; nt < 4; ++nt)
#pragma unroll
      for (int r = 0; r < 4; ++r) acc[mt][nt][r] = 0.f;

  auto loadB = [&](short8* B, int ks) {
    int t, chunk;
    if (C == 64) {
      t = ks >> 1;
      chunk = ((ks & 1) << 2) + quad;
    } else {
      t = ks * 4 + quad;
      if (t > 8) t = 8;  // dummy taps: A rows are zero
      chunk = 0;
    }
    int dy = t / 3, dx = t - (t / 3) * 3;
#pragma unroll
    for (int nt = 0; nt < 4; ++nt) {
      int c = nt * 16 + l15 + dx;
      int slot = (C == 64)
                     ? ((rowIdx + dy) * SROW + c * 8 + (chunk ^ (c & 7)))
                     : ((rowIdx + dy) * 66 + c);
      B[nt] = *(const short8*)&xs[(size_t)slot * 8];
    }
  };

  short8 Bbuf[2][4];
  loadB(Bbuf[0], 0);
#pragma unroll
  for (int ks = 0; ks < KS; ++ks) {
    if (ks + 1 < KS) loadB(Bbuf[(ks + 1) & 1], ks + 1);
    const int slot = ks % W;  // compile-time under full unroll
#pragma unroll
    for (int nt = 0; nt < 4; ++nt)
#pragma unroll
      for (int mt = 0; mt < 2; ++mt)
        acc[mt][nt] = __builtin_amdgcn_mfma_f32_16x16x32_bf16(
            Wa[mt][slot], Bbuf[ks & 1][nt], acc[mt][nt], 0, 0, 0);
    if (ks + W < KS) loadA(slot, ks + W);  // rolling refill (W-ks lead)
  }

  // epilogue: C/D layout col=l15 (pixel), row=quad*4+reg (oc)
  const int yw = y0 + rowIdx;
#pragma unroll
  for (int mt = 0; mt < 2; ++mt) {
    const float4 bb = *(const float4*)&bias[ocH * 32 + mt * 16 + quad * 4];
#pragma unroll
    for (int nt = 0; nt < 4; ++nt) {
      int px = x0 + nt * 16 + l15;
      size_t base = ((size_t)b * PP + (size_t)(yw + 1) * PW + (px + 1)) * 64 +
                    ocH * 32 + mt * 16 + quad * 4;
      float v0 = acc[mt][nt][0] + bb.x;
      float v1 = acc[mt][nt][1] + bb.y;
      float v2 = acc[mt][nt][2] + bb.z;
      float v3 = acc[mt][nt][3] + bb.w;
      if (RELU) {
        v0 = fmaxf(v0, 0.f); v1 = fmaxf(v1, 0.f);
        v2 = fmaxf(v2, 0.f); v3 = fmaxf(v3, 0.f);
      }
      if (RESID) {
        short4v rv = *(const short4v*)&resid[base];
        v0 += bf2f((ushort)rv[0]); v1 += bf2f((ushort)rv[1]);
        v2 += bf2f((ushort)rv[2]); v3 += bf2f((ushort)rv[3]);
      }
      short4v o;
      o[0] = (short)f2bf(v0); o[1] = (short)f2bf(v1);
      o[2] = (short)f2bf(v2); o[3] = (short)f2bf(v3);
      *(short4v*)&out[base] = o;
    }
  }
}

// ---------------------------------------------------------------------------
// Fused out-conv (64->225 pad 256) + abs-softmax + 15x15 kernel-conv.
// (unchanged from R8: B from LDS swizzled, A register window, vectorized
// transposed-tap consumer)
// ---------------------------------------------------------------------------
__global__ __launch_bounds__(256, 2) void out_kc_k(
    const ushort* __restrict__ x, const ushort* __restrict__ wf,
    const float* __restrict__ b_out, const float* __restrict__ data,
    float* __restrict__ pred) {
  __shared__ __align__(16) char uni[64 * 264 * 2];
  __shared__ __align__(16) _Float16 dshT[3 * 80 * 20];  // [ch][col][row+pad]
  __shared__ float bsh[256];
  ushort* xs = (ushort*)uni;
  _Float16* coreSh = (_Float16*)uni;

  const int tid = threadIdx.x;
  const int wave = tid >> 6, lane = tid & 63;
  const int quad = lane >> 4, l15 = lane & 15;
  const int x0 = blockIdx.x * 64, y = blockIdx.y, b = blockIdx.z;
  const ushort* wfl = wf + (size_t)lane * 8;

  // stage x tile: 3 padded rows y..y+2, cols x0..x0+65 (swizzled)
  for (int s0 = wave * 64; s0 < 3 * 528; s0 += 256) {
    int s = s0 + lane;
    int row = s / 528;
    int r = s - row * 528;
    int col = r >> 3;
    int chunk = (r & 7) ^ (col & 7);
    const ushort* g = x + ((size_t)b * PP + (size_t)(y + row) * PW +
                           (x0 + col)) * 64 + chunk * 8;
    GLD_LDS(g, &xs[(size_t)s0 * 8]);
  }
  bsh[tid] = (tid < 225) ? b_out[tid] : 0.f;
  // stage data tile transposed: dshT[(ch*80+col)*20 + r]
  for (int i = tid; i < 3 * 16 * 78; i += 256) {
    int ch = i / 1248;
    int rem = i - ch * 1248;
    int r = rem / 78;
    int col = rem - r * 78;
    int gy = y - 7 + r, gx = x0 - 7 + col;
    float v = 0.f;
    if ((unsigned)gy < (unsigned)HW && (unsigned)gx < (unsigned)HW)
      v = data[((b * 3 + ch) << 16) + (gy << 8) + gx];
    dshT[(ch * 80 + col) * 20 + r] = (_Float16)v;
  }

  // preload A window (wave w -> oc group w: g = wave*4 + mt, NG = 16)
  short8 Wa[4][4];
  auto loadA = [&](int slot, int ks) {
#pragma unroll
    for (int mt = 0; mt < 4; ++mt)
      Wa[mt][slot] =
          *(const short8*)&wfl[(size_t)((ks * 16 + wave * 4 + mt)) * 512];
  };
#pragma unroll
  for (int ks = 0; ks < 4; ++ks) loadA(ks, ks);

  __syncthreads();

  f32x4 acc[4][4];
#pragma unroll
  for (int mt = 0; mt < 4; ++mt)
#pragma unroll
    for (int nt = 0; nt < 4; ++nt)
#pragma unroll
      for (int r = 0; r < 4; ++r) acc[mt][nt][r] = 0.f;

  auto loadB = [&](short8* B, int ks) {
    int t = ks >> 1;
    int dy = t / 3, dx = t - (t / 3) * 3;
    int chunk = ((ks & 1) << 2) + quad;
#pragma unroll
    for (int nt = 0; nt < 4; ++nt) {
      int c = nt * 16 + l15 + dx;
      int slot = dy * 528 + c * 8 + (chunk ^ (c & 7));
      B[nt] = *(const short8*)&xs[(size_t)slot * 8];
    }
  };

  short8 Bbuf[2][4];
  loadB(Bbuf[0], 0);
#pragma unroll
  for (int ks = 0; ks < 18; ++ks) {
    if (ks + 1 < 18) loadB(Bbuf[(ks + 1) & 1], ks + 1);
    const int slot = ks % 4;
#pragma unroll
    for (int nt = 0; nt < 4; ++nt)
#pragma unroll
      for (int mt = 0; mt < 4; ++mt)
        acc[mt][nt] = __builtin_amdgcn_mfma_f32_16x16x32_bf16(
            Wa[mt][slot], Bbuf[ks & 1][nt], acc[mt][nt], 0, 0, 0);
    if (ks + 4 < 18) loadA(slot, ks + 4);
  }
  __syncthreads();  // retire xs reads before aliasing as coreSh

  // producer: |core + bias| (masked -> -1e4) as fp16, row stride 264
#pragma unroll
  for (int mt = 0; mt < 4; ++mt) {
    int c0 = wave * 64 + mt * 16 + quad * 4;
#pragma unroll
    for (int nt = 0; nt < 4; ++nt) {
      int px = nt * 16 + l15;
      h4 hv;
#pragma unroll
      for (int r = 0; r < 4; ++r) {
        int c = c0 + r;
        float a = acc[mt][nt][r] + bsh[c];
        a = (c < 225) ? fabsf(a) : -1e4f;
        hv[r] = (_Float16)a;
      }
      *(h4*)&coreSh[px * 264 + c0] = hv;
    }
  }
  __syncthreads();

  // consumer: px = wave*16+l15; quad = tap-row group
  const int px = wave * 16 + l15;
  const int q = quad;
  h4 vals4[15];
#pragma unroll
  for (int k = 0; k < 15; ++k)
    vals4[k] = *(h4*)&coreSh[px * 264 + q * 60 + k * 4];

  float m = 0.f;
#pragma unroll
  for (int k = 0; k < 15; ++k)
#pragma unroll
    for (int z = 0; z < 4; ++z) m = fmaxf(m, (float)vals4[k][z]);
  m = fmaxf(m, __shfl_xor(m, 16));
  m = fmaxf(m, __shfl_xor(m, 32));

  float e[60];
  float l = 0.f;
#pragma unroll
  for (int k = 0; k < 15; ++k)
#pragma unroll
    for (int z = 0; z < 4; ++z) {
      float t = __expf((float)vals4[k][z] - m);
      e[k * 4 + z] = t;
      l += t;
    }

  float p0 = 0.f, p1 = 0.f, p2 = 0.f;
#pragma unroll
  for (int dj = 0; dj < 15; ++dj) {
    h4 d0 = *(h4*)&dshT[(0 * 80 + px + dj) * 20 + 4 * q];
    h4 d1 = *(h4*)&dshT[(1 * 80 + px + dj) * 20 + 4 * q];
    h4 d2 = *(h4*)&dshT[(2 * 80 + px + dj) * 20 + 4 * q];
#pragma unroll
    for (int rr = 0; rr < 4; ++rr) {
      float ev = e[rr * 15 + dj];
      p0 += ev * (float)d0[rr];
      p1 += ev * (float)d1[rr];
      p2 += ev * (float)d2[rr];
    }
  }
  l += __shfl_xor(l, 16);  l += __shfl_xor(l, 32);
  p0 += __shfl_xor(p0, 16); p0 += __shfl_xor(p0, 32);
  p1 += __shfl_xor(p1, 16); p1 += __shfl_xor(p1, 32);
  p2 += __shfl_xor(p2, 16); p2 += __shfl_xor(p2, 32);

  if (q == 0) {
    float inv = 1.f / l;
    int pix = (y << 8) + x0 + px;
    pred[((b * 3 + 0) << 16) + pix] = p0 * inv;
    pred[((b * 3 + 1) << 16) + pix] = p1 * inv;
    pred[((b * 3 + 2) << 16) + pix] = p2 * inv;
  }
}

extern "C" void kernel_launch(void* const* d_in, const int* in_sizes, int n_in,
                              void* d_out, int out_size, void* d_ws,
                              size_t ws_size, hipStream_t stream) {
  const float* data_with_est = (const float*)d_in[0];
  const float* data = (const float*)d_in[1];
  const float* b_first = (const float*)d_in[3];
  const float* ba[3] = {(const float*)d_in[5], (const float*)d_in[9],
                        (const float*)d_in[13]};
  const float* bb[3] = {(const float*)d_in[7], (const float*)d_in[11],
                        (const float*)d_in[15]};
  const float* b_out = (const float*)d_in[17];

  float* out = (float*)d_out;
  float* pred = out + 4 * 3 * NPIX;

  // workspace layout (ushort units)
  ushort* x = (ushort*)d_ws;                 // 4*PP*64
  ushort* y = x + (size_t)4 * PP * 64;       // 4*PP*64
  ushort* xp = y + (size_t)4 * PP * 64;      // 4*PP*8
  ushort* Wb = xp + (size_t)4 * PP * 8;      // packed weights base
  ushort* Wp1 = Wb;                          //   +0      (6144)
  ushort* Wpr = Wb + 6144;                   //   +6144   (6*36864)
  ushort* Wpo = Wb + 227328;                 //   +227328 (147456)

  // fused prep (2 launches)
  prep_pack_k<<<1809, 256, 0, stream>>>(data_with_est, xp, x, y,
                                        (const float4*)data, (float4*)out);
  W8 ws;
  ws.w[0] = (const float*)d_in[2];
  ws.w[1] = (const float*)d_in[4];  ws.w[2] = (const float*)d_in[6];
  ws.w[3] = (const float*)d_in[8];  ws.w[4] = (const float*)d_in[10];
  ws.w[5] = (const float*)d_in[12]; ws.w[6] = (const float*)d_in[14];
  ws.w[7] = (const float*)d_in[16];
  prep_w_k<<<1464, 256, 0, stream>>>(ws, Wb);

  dim3 cgrid(4, 128, 4), cblk(256);
  // first conv 6->64 (C padded to 8, K padded to 96)
  conv_mfma_k<8, 3, false, false>
      <<<cgrid, cblk, 0, stream>>>(xp, Wp1, b_first, nullptr, x);
  // 3 residual blocks
  for (int i = 0; i < 3; ++i) {
    conv_mfma_k<64, 18, true, false><<<cgrid, cblk, 0, stream>>>(
        x, Wpr + (2 * i) * 36864, ba[i], nullptr, y);
    conv_mfma_k<64, 18, false, true><<<cgrid, cblk, 0, stream>>>(
        y, Wpr + (2 * i + 1) * 36864, bb[i], x, x);
  }
  // fused out-conv + softmax + kernel-conv
  out_kc_k<<<dim3(4, HW, 4), 256, 0, stream>>>(x, Wpo, b_out, data, pred);
}